// Round 15
// baseline (648.164 us; speedup 1.0000x reference)
//
#include <hip/hip_runtime.h>
#include <hip/hip_bf16.h>
#include <cstdint>

typedef unsigned short u16;
typedef __attribute__((ext_vector_type(4))) float f32x4;
typedef __attribute__((ext_vector_type(8))) short s16x8;

#define DEV __device__ __forceinline__

DEV u16 f2bf(float x) {                       // RNE f32 -> bf16
  unsigned u = __float_as_uint(x);
  u += 0x7FFFu + ((u >> 16) & 1u);
  return (u16)(u >> 16);
}
DEV float bf2f(u16 b) { return __uint_as_float(((unsigned)b) << 16); }

DEV void gload16(const void* g, void* l) {    // async global->LDS, 16B/lane
  __builtin_amdgcn_global_load_lds(
      (const __attribute__((address_space(1))) void*)g,
      (__attribute__((address_space(3))) void*)l, 16, 0, 0);
}

template<bool MAXOP>
DEV float blockRed256(float v) {
  for (int o = 32; o; o >>= 1) {
    float t = __shfl_xor(v, o);
    v = MAXOP ? fmaxf(v, t) : v + t;
  }
  __shared__ float s[4];
  __syncthreads();
  if ((threadIdx.x & 63) == 0) s[threadIdx.x >> 6] = v;
  __syncthreads();
  return MAXOP ? fmaxf(fmaxf(s[0], s[1]), fmaxf(s[2], s[3]))
               : (s[0] + s[1] + s[2] + s[3]);
}

// ------------------------------------------------- weight transpose ------
// batched: z selects (in,out) pair. f32 (K,N) -> bf16 (N,K). ilv: swiglu.
struct WtB { const float* in[8]; u16* out[8]; };
__global__ __launch_bounds__(256) void wtransb_k(WtB wb, int K, int N, int ilv) {
  const float* __restrict__ in = wb.in[blockIdx.z];
  u16* __restrict__ out = wb.out[blockIdx.z];
  __shared__ float t[64][68];
  const int n0 = blockIdx.x * 64, k0 = blockIdx.y * 64;
  const int tt = threadIdx.x;
  const int kl = tt >> 4, nl = (tt & 15) * 4;
#pragma unroll
  for (int i = 0; i < 4; ++i) {
    int k = kl + i * 16;
    float4 v{0.f, 0.f, 0.f, 0.f};
    if (n0 + nl + 3 < N) {
      v = *(const float4*)(in + (long long)(k0 + k) * N + n0 + nl);
    } else {
      for (int j = 0; j < 4; ++j)
        if (n0 + nl + j < N) ((float*)&v)[j] = in[(long long)(k0 + k) * N + n0 + nl + j];
    }
    t[nl + 0][k] = v.x; t[nl + 1][k] = v.y; t[nl + 2][k] = v.z; t[nl + 3][k] = v.w;
  }
  __syncthreads();
  const int n = tt >> 2, kq = (tt & 3) * 16;
  if (n0 + n < N) {
    s16x8 o0, o1;
#pragma unroll
    for (int j = 0; j < 8; ++j) { o0[j] = (short)f2bf(t[n][kq + j]); o1[j] = (short)f2bf(t[n][kq + 8 + j]); }
    int c = n0 + n;
    int r = ilv ? ((((c & 4095) >> 4) << 5) + ((c >> 12) << 4) + (c & 15)) : c;
    u16* op = out + (long long)r * K + k0 + kq;
    *(s16x8*)op = o0; *(s16x8*)(op + 8) = o1;
  }
}

// ---------------------------------------------------------------- GEMM ----
struct GemmP {
  const u16* A; int lda; long long sAz;
  const u16* B; int ldb; long long sBz;
  void* C; int ldc; long long sCz;
  int M, N, K;
  int gqa;      // 1: B batch index = (z>>4)*4 + ((z&15)>>2)   (GQA 16q/4kv)
  int czmode;   // 1: C base = b*1048576 + h*64  (attn concat store)
  const float *p0, *p1, *p2, *p3;
  float scale; int eidx;
  u16 *aux0, *aux1, *aux2;   // qkv routing: qpre, kpre, vT ; EPI11: scores
  const int* cnt;            // per-expert routed token counts (MoE)
  const int* s2t;            // slot -> token map (MoE A-row gather)
  int xcdr;                  // 1: XCD-contiguous bx raster (by fastest)
};

// ---- 128xTN tile, 4 waves — ALL GEMMs ----------------------------------
// PIPE=0: double-buffered 2-phase (front/attn). PIPE=1: ring-3 LDS with
// counted vmcnt(6) (T3/T4, schedule copied from the proven gemm256_k):
// loads for tile ts+2 stay in flight across the barrier; never drain to 0
// in steady state. Used by the MoE GEMMs (latency-exposed at ~2 blocks/CU).
// EPI: 0 bf16, 1 f32, 5 scaled bf16, 8 fused swiglu (interleaved B rows),
//      9 batched3 f32 (+pwb if z==2), 10 gate+qkv combined,
//      11 PV with fused softmax (A rows block-private).
// Routed MoE: p.cnt -> early exit; p.s2t -> A-row gather; p.xcdr -> raster.
template<int EPI, int TN, int PIPE = 0>
__global__ __launch_bounds__(256) void gemm_k(GemmP p) {
  constexpr int NF = TN / 32;                 // B fragments per wave
  constexpr int NB = PIPE ? 3 : 2;
  __shared__ u16 Al[NB][128 * 64];
  __shared__ u16 Bl[NB][TN * 64];
  __shared__ float sminv[128];
  int bx = blockIdx.x, by = blockIdx.y, z = blockIdx.z;
  if (p.xcdr) {
    const int nx = gridDim.x, ny = gridDim.y;
    const int chunk = nx >> 3;
    int flat = (blockIdx.z * ny + blockIdx.y) * nx + blockIdx.x;
    int c = flat & 7, i = flat >> 3;
    by = i % ny;
    int rest = i / ny;
    bx = c * chunk + rest % chunk;
    z = rest / chunk;
  }
  const int t = threadIdx.x;
  const int lane = t & 63, wid = t >> 6;
  const int wm = wid >> 1, wn = wid & 1;
  const int m0 = by * 128, n0 = bx * TN;
  if (p.cnt && m0 >= p.cnt[p.eidx + z]) return;      // routed-MoE early exit
  const int* s2te = p.s2t ? p.s2t + (p.eidx + z) * 2048 : nullptr;

  const u16* Ab = p.A + (long long)z * p.sAz;
  const u16* Bb = p.B + (p.gqa ? (long long)(((z >> 4) << 2) + ((z & 15) >> 2)) * p.sBz
                               : (long long)z * p.sBz);
  const int sr = lane >> 3;                 // sub-row 0..7
  const int sg = (lane & 7) ^ sr;           // pre-swizzled k-group
  long long pao[4]; int lao[4];
  long long pbo[NF]; int lbo[NF];
#pragma unroll
  for (int c = 0; c < 4; ++c) {
    int rbase = c * 32 + wid * 8;
    int ra = m0 + rbase + sr; if (ra > p.M - 1) ra = p.M - 1;
    if (s2te) ra = s2te[ra];                // slot -> token gather
    pao[c] = (long long)ra * p.lda + sg * 8;
    lao[c] = rbase * 64;
  }
#pragma unroll
  for (int c = 0; c < NF; ++c) {
    int rbase = c * 32 + wid * 8;
    int rb = n0 + rbase + sr; if (rb > p.N - 1) rb = p.N - 1;
    pbo[c] = (long long)rb * p.ldb + sg * 8;
    lbo[c] = rbase * 64;
  }

  if (EPI == 11) {
    // fused softmax over this block's exclusive 128 score rows (K=1024).
    int r = t >> 1, h2 = t & 1;
    u16* rp = p.aux0 + (long long)z * p.sAz + (long long)(m0 + r) * 1024 + h2 * 8;
    float mx = -1e30f;
    for (int it = 0; it < 64; ++it) {
      s16x8 v = *(const s16x8*)(rp + it * 16);
#pragma unroll
      for (int q = 0; q < 8; ++q) mx = fmaxf(mx, bf2f((u16)v[q]));
    }
    mx = fmaxf(mx, __shfl_xor(mx, 1));
    float sum = 0.f;
    for (int it = 0; it < 64; ++it) {
      s16x8 v = *(s16x8*)(rp + it * 16);
      s16x8 o;
#pragma unroll
      for (int q = 0; q < 8; ++q) {
        float e = __expf(bf2f((u16)v[q]) - mx);
        sum += e;
        o[q] = (short)f2bf(e);
      }
      *(s16x8*)(rp + it * 16) = o;
    }
    sum += __shfl_xor(sum, 1);
    if (!h2) sminv[r] = 1.f / sum;
    asm volatile("s_waitcnt vmcnt(0)" ::: "memory");  // writes visible in L2
    __syncthreads();
  }

  f32x4 acc[4][NF];
#pragma unroll
  for (int i = 0; i < 4; ++i)
#pragma unroll
    for (int j = 0; j < NF; ++j) acc[i][j] = f32x4{0.f, 0.f, 0.f, 0.f};

  const int lr = lane & 15, lk = lane >> 4;

  if constexpr (PIPE) {
    // ---- ring-3 counted-vmcnt pipeline (proven gemm256_k schedule) ----
    const int NT = p.K >> 6;
#pragma unroll
    for (int c = 0; c < 4; ++c) gload16(Ab + pao[c], &Al[0][lao[c]]);
#pragma unroll
    for (int c = 0; c < NF; ++c) gload16(Bb + pbo[c], &Bl[0][lbo[c]]);
    if (NT > 1) {
#pragma unroll
      for (int c = 0; c < 4; ++c) gload16(Ab + pao[c] + 64, &Al[1][lao[c]]);
#pragma unroll
      for (int c = 0; c < NF; ++c) gload16(Bb + pbo[c] + 64, &Bl[1][lbo[c]]);
    }
    asm volatile("s_waitcnt vmcnt(6)" ::: "memory");   // batch 0 landed
    __builtin_amdgcn_s_barrier();
    int cur = 0, stg = 2;
    for (int ts = 0; ts < NT; ++ts) {
      if (ts + 2 < NT) {               // stage batch ts+2, keep 6 in flight
        long long ko = (long long)(ts + 2) * 64;
#pragma unroll
        for (int c = 0; c < 4; ++c) gload16(Ab + pao[c] + ko, &Al[stg][lao[c]]);
#pragma unroll
        for (int c = 0; c < NF; ++c) gload16(Bb + pbo[c] + ko, &Bl[stg][lbo[c]]);
        asm volatile("s_waitcnt vmcnt(6)" ::: "memory");  // ts+1 landed
      } else {
        asm volatile("s_waitcnt vmcnt(0)" ::: "memory");  // tail drain
      }
#pragma unroll
      for (int kk = 0; kk < 2; ++kk) {
        s16x8 af[4], bfr[NF];
        int g = kk * 4 + lk;
#pragma unroll
        for (int i = 0; i < 4; ++i) {
          int ra = wm * 64 + i * 16 + lr;
          af[i] = *(const s16x8*)&Al[cur][ra * 64 + ((g ^ (ra & 7)) * 8)];
        }
#pragma unroll
        for (int j = 0; j < NF; ++j) {
          int rb = wn * (TN / 2) + j * 16 + lr;
          bfr[j] = *(const s16x8*)&Bl[cur][rb * 64 + ((g ^ (rb & 7)) * 8)];
        }
        __builtin_amdgcn_s_setprio(1);
#pragma unroll
        for (int i = 0; i < 4; ++i)
#pragma unroll
          for (int j = 0; j < NF; ++j)
            acc[i][j] = __builtin_amdgcn_mfma_f32_16x16x32_bf16(af[i], bfr[j], acc[i][j], 0, 0, 0);
        __builtin_amdgcn_s_setprio(0);
      }
      asm volatile("s_waitcnt lgkmcnt(0)" ::: "memory");
      __builtin_amdgcn_s_barrier();
      cur = (cur + 1 == 3) ? 0 : cur + 1;
      stg = (stg + 1 == 3) ? 0 : stg + 1;
    }
  } else {
    // ---- 2-phase double buffer ----
#pragma unroll
    for (int c = 0; c < 4; ++c) gload16(Ab + pao[c], &Al[0][lao[c]]);
#pragma unroll
    for (int c = 0; c < NF; ++c) gload16(Bb + pbo[c], &Bl[0][lbo[c]]);
    __syncthreads();
    int cur = 0;
    for (int k0 = 0; k0 < p.K; k0 += 64) {
      int nxt = cur ^ 1;
      if (k0 + 64 < p.K) {
#pragma unroll
        for (int c = 0; c < 4; ++c) gload16(Ab + pao[c] + k0 + 64, &Al[nxt][lao[c]]);
#pragma unroll
        for (int c = 0; c < NF; ++c) gload16(Bb + pbo[c] + k0 + 64, &Bl[nxt][lbo[c]]);
      }
#pragma unroll
      for (int kk = 0; kk < 2; ++kk) {
        s16x8 af[4], bfr[NF];
        int g = kk * 4 + lk;
#pragma unroll
        for (int i = 0; i < 4; ++i) {
          int ra = wm * 64 + i * 16 + lr;
          af[i] = *(const s16x8*)&Al[cur][ra * 64 + ((g ^ (ra & 7)) * 8)];
        }
#pragma unroll
        for (int j = 0; j < NF; ++j) {
          int rb = wn * (TN / 2) + j * 16 + lr;
          bfr[j] = *(const s16x8*)&Bl[cur][rb * 64 + ((g ^ (rb & 7)) * 8)];
        }
#pragma unroll
        for (int i = 0; i < 4; ++i)
#pragma unroll
          for (int j = 0; j < NF; ++j)
            acc[i][j] = __builtin_amdgcn_mfma_f32_16x16x32_bf16(af[i], bfr[j], acc[i][j], 0, 0, 0);
      }
      __syncthreads();
      cur = nxt;
    }
  }

  long long cb;
  if (p.czmode == 1) { int b = z >> 4, h = z & 15; cb = (long long)b * 1048576 + h * 64; }
  else cb = (long long)z * p.sCz;
  const int lq = lane >> 4;

  if (EPI == 8) {                      // fused swiglu (interleaved B rows)
#pragma unroll
    for (int i = 0; i < 4; ++i) {
#pragma unroll
      for (int u = 0; u < NF / 2; ++u) {
        int pcol = (n0 >> 1) + wn * (TN / 4) + u * 16 + lr;
#pragma unroll
        for (int q = 0; q < 4; ++q) {
          int row = m0 + wm * 64 + i * 16 + lq * 4 + q;
          float a = acc[i][2 * u][q], gg = acc[i][2 * u + 1][q];
          ((u16*)p.C)[cb + (long long)row * p.ldc + pcol] =
              f2bf(a / (1.f + __expf(-a)) * gg);
        }
      }
    }
    return;
  }
#pragma unroll
  for (int i = 0; i < 4; ++i) {
#pragma unroll
    for (int j = 0; j < NF; ++j) {
      int col = n0 + wn * (TN / 2) + j * 16 + lr;
      if (col >= p.N) continue;
#pragma unroll
      for (int q = 0; q < 4; ++q) {
        int row = m0 + wm * 64 + i * 16 + lq * 4 + q;
        float v = acc[i][j][q];
        if (EPI == 0) {          // plain bf16 store
          ((u16*)p.C)[cb + (long long)row * p.ldc + col] = f2bf(v);
        } else if (EPI == 1) {   // plain f32 store
          ((float*)p.C)[cb + (long long)row * p.ldc + col] = v;
        } else if (EPI == 5) {   // scaled bf16 (attention scores)
          ((u16*)p.C)[cb + (long long)row * p.ldc + col] = f2bf(v * p.scale);
        } else if (EPI == 9) {   // batched3 {ssd_o, o, pw}: f32 (+bias z==2)
          float add = (z == 2) ? p.p0[col] : 0.f;
          ((float*)p.C)[cb + (long long)row * p.ldc + col] = v + add;
        } else if (EPI == 11) {  // PV: row-normalize by softmax denom
          float sc = sminv[wm * 64 + i * 16 + lq * 4 + q];
          ((u16*)p.C)[cb + (long long)row * p.ldc + col] = f2bf(v * sc);
        } else if (EPI == 10) {  // gate (col<1024) + qkv routing
          if (col < 1024) {
            float gg = 1.f / (1.f + __expf(-(v + p.p0[col])));
            float yv = p.p1[row * 16 + (col >> 6)] +
                       p.p2[(long long)row * 1024 + col] * p.p3[col >> 6];
            ((u16*)p.C)[(long long)row * p.ldc + col] = f2bf(gg * yv);
          } else {
            int c2 = col - 1024;
            if (c2 < 1024) {
              p.aux0[(long long)row * 1024 + c2] = f2bf(v);
            } else if (c2 < 1280) {
              p.aux1[(long long)row * 256 + (c2 - 1024)] = f2bf(v);
            } else {
              int cc = c2 - 1280;
              int b = row >> 10, l = row & 1023, kvh = cc >> 6, d = cc & 63;
              p.aux2[(((long long)(b * 4 + kvh) * 64 + d) << 10) + l] = f2bf(v);
            }
          }
        }
      }
    }
  }
}

// --------------------------------------------------------- small kernels --
__global__ void rms1router_k(const float* x, const float* goal, const float* w,
                             const float* rw, float* xn, u16* xnb, float* wout) {
  int m = blockIdx.x, t = threadIdx.x;
  const float* xr = x + (long long)m * 1024;
  float v[4]; float ss = 0.f;
#pragma unroll
  for (int i = 0; i < 4; ++i) { v[i] = xr[t + i * 256]; ss += v[i] * v[i]; }
  ss = blockRed256<false>(ss);
  float r = rsqrtf(ss * (1.f / 1024.f) + 1e-6f);
  float a[4] = {0.f, 0.f, 0.f, 0.f};
#pragma unroll
  for (int i = 0; i < 4; ++i) {
    int c = t + i * 256;
    float o = v[i] * r * w[c] + goal[(long long)m * 1024 + c];
    xn[(long long)m * 1024 + c] = o;
    xnb[(long long)m * 1024 + c] = f2bf(o);
    const float* rr = rw + c * 4;
    a[0] += o * rr[0]; a[1] += o * rr[1]; a[2] += o * rr[2]; a[3] += o * rr[3];
  }
#pragma unroll
  for (int j = 0; j < 4; ++j) a[j] = blockRed256<false>(a[j]);
  if (t == 0) {
    float mx = fmaxf(fmaxf(a[0], a[1]), fmaxf(a[2], a[3]));
    float e[4]; float s = 0.f;
    for (int j = 0; j < 4; ++j) { e[j] = __expf(a[j] - mx); s += e[j]; }
    const float mix[4] = {0.5f, 0.2f, 0.15f, 0.15f};
    float ws = 0.f;
    for (int j = 0; j < 4; ++j) { e[j] = e[j] / s * mix[j]; ws += e[j]; }
    for (int j = 0; j < 4; ++j) wout[m * 4 + j] = e[j] / ws;
  }
}

DEV float softplus_f(float x) { return x > 15.f ? x : log1pf(__expf(x)); }

__global__ void scanA_k(const float* ssm, const float* A, float* aprod, float* sloc) {
  int blk = blockIdx.x, n = threadIdx.x;
  int c = blk & 63, h = (blk >> 6) & 15, b = blk >> 10;
  float Ah = A[h * 64 + n];
  float ap = 1.f, s = 0.f;
  int l0 = c * 16;
  for (int j = 0; j < 16; ++j) {
    long long off = (long long)(b * 1024 + l0 + j) * 144;
    float d = softplus_f(ssm[off + 128 + h] + ssm[off + n]);
    float a = __expf(d * Ah);
    s = a * s + d * d;
    ap *= a;
  }
  long long o = (long long)blk * 64 + n;
  aprod[o] = ap; sloc[o] = s;
}

__global__ void scanB_k(const float* aprod, const float* sloc, float* cin) {
  int bh = blockIdx.x, n = threadIdx.x;
  float carry = 0.f;
  for (int c = 0; c < 64; ++c) {
    long long o = (long long)(bh * 64 + c) * 64 + n;
    cin[o] = carry;
    carry = aprod[o] * carry + sloc[o];
  }
}

__global__ void scanC_k(const float* ssm, const float* A, const float* cin, float* ysm) {
  int blk = blockIdx.x, n = threadIdx.x;
  int c = blk & 63, h = (blk >> 6) & 15, b = blk >> 10;
  float Ah = A[h * 64 + n];
  float s = cin[(long long)blk * 64 + n];
  int l0 = c * 16;
  for (int j = 0; j < 16; ++j) {
    long long off = (long long)(b * 1024 + l0 + j) * 144;
    float d = softplus_f(ssm[off + 128 + h] + ssm[off + n]);
    float a = __expf(d * Ah);
    s = a * s + d * d;
    float yv = s * ssm[off + 64 + n];
    for (int o2 = 32; o2; o2 >>= 1) yv += __shfl_xor(yv, o2);
    if (n == 0) ysm[(long long)(b * 1024 + l0 + j) * 16 + h] = yv;
  }
}

__global__ void rtab_k(float2* rt) {
  int i = blockIdx.x * 256 + threadIdx.x;    // 32768 = 1024 x 32
  int l = i >> 5, f = i & 31;
  float fr = (float)l * powf(10000.f, -(float)f * (1.f / 32.f));
  rt[i] = float2{cosf(fr), sinf(fr)};
}

__global__ void rope_k(const u16* qpre, const u16* kpre, const float* qnw,
                       const float* knw, const float2* rtab, u16* qro, u16* kro) {
  int rid = blockIdx.x * 4 + (threadIdx.x >> 6);
  int lane = threadIdx.x & 63;
  float v; const float* nw; int l; u16* dst;
  if (rid < 32768) {
    int b = rid >> 14, h = (rid >> 10) & 15; l = rid & 1023;
    v = bf2f(qpre[(long long)(b * 1024 + l) * 1024 + h * 64 + lane]);
    nw = qnw; dst = qro + (long long)rid * 64;
  } else {
    int r2 = rid - 32768;
    int b = r2 >> 12, kvh = (r2 >> 10) & 3; l = r2 & 1023;
    v = bf2f(kpre[(long long)(b * 1024 + l) * 256 + kvh * 64 + lane]);
    nw = knw; dst = kro + (long long)r2 * 64;
  }
  float ss = v * v;
  for (int o = 32; o; o >>= 1) ss += __shfl_xor(ss, o);
  float r = rsqrtf(ss * (1.f / 64.f) + 1e-6f);
  float vn = v * r * nw[lane];
  float pt = __shfl_xor(vn, 32);
  float2 cs = rtab[l * 32 + (lane & 31)];
  float o2 = vn * cs.x + ((lane < 32) ? -pt : pt) * cs.y;
  dst[lane] = f2bf(o2);
}

__global__ void conv_k(const float* xn, const float* dww, const float* dwb, u16* outb) {
  int m = blockIdx.x; int l = m & 1023;
#pragma unroll
  for (int i = 0; i < 4; ++i) {
    int d = threadIdx.x + i * 256;
    float xm = l > 0    ? xn[(long long)(m - 1) * 1024 + d] : 0.f;
    float x0 =            xn[(long long)m * 1024 + d];
    float xp = l < 1023 ? xn[(long long)(m + 1) * 1024 + d] : 0.f;
    float dv = xm * dww[d * 3] + x0 * dww[d * 3 + 1] + xp * dww[d * 3 + 2] + dwb[d];
    outb[(long long)m * 1024 + d] = f2bf(dv / (1.f + __expf(-dv)));
  }
}

__global__ void mixmoegate_k(const float* x, const float* w, const float* o3,
                             const float* mem, const float* n2w, const float* mg,
                             float* x2, u16* x2b, float* wf) {
  int m = blockIdx.x, t = threadIdx.x;
  float w0 = w[m * 4], w1 = w[m * 4 + 1], w2 = w[m * 4 + 2], w3 = w[m * 4 + 3];
  float ss = 0.f, a[4] = {0.f, 0.f, 0.f, 0.f};
#pragma unroll
  for (int j = 0; j < 4; ++j) {
    int c = t + j * 256;
    long long i = (long long)m * 1024 + c;
    float v = x[i] + w0 * o3[i] + w1 * o3[i + 2097152] + w2 * o3[i + 4194304] +
              w3 * mem[i];
    x2[i] = v; x2b[i] = f2bf(v);
    ss += v * v;
    float vw = v * n2w[c];
    const float* g = mg + c * 4;
    a[0] += vw * g[0]; a[1] += vw * g[1]; a[2] += vw * g[2]; a[3] += vw * g[3];
  }
  ss = blockRed256<false>(ss);
#pragma unroll
  for (int j = 0; j < 4; ++j) a[j] = blockRed256<false>(a[j]);
  if (t == 0) {
    float r = rsqrtf(ss * (1.f / 1024.f) + 1e-6f);
    float mx = -1e30f;
    for (int j = 0; j < 4; ++j) { a[j] *= r; mx = fmaxf(mx, a[j]); }
    float e[4]; float s = 0.f;
    for (int j = 0; j < 4; ++j) { e[j] = __expf(a[j] - mx); s += e[j]; }
    for (int j = 0; j < 4; ++j) e[j] /= s;
    int i0 = 0;
    for (int j = 1; j < 4; ++j) if (e[j] > e[i0]) i0 = j;
    int i1 = -1;
    for (int j = 0; j < 4; ++j) { if (j == i0) continue; if (i1 < 0 || e[j] > e[i1]) i1 = j; }
    for (int j = 0; j < 4; ++j) wf[m * 4 + j] = (j == i0 || j == i1) ? e[j] : 0.f;
  }
}

// deterministic expert routing: ballot prefix-scan. 1 block, 4 waves.
__global__ void escan_k(const float* wf, int* cnt, int* s2t, int* t2s) {
  int e = threadIdx.x >> 6, lane = threadIdx.x & 63;
  int base = 0;
  for (int c = 0; c < 32; ++c) {
    int m = c * 64 + lane;
    bool r = wf[m * 4 + e] != 0.f;
    unsigned long long mask = __ballot(r);
    int pre = __popcll(mask & ((1ull << lane) - 1ull));
    if (r) { s2t[e * 2048 + base + pre] = m; t2s[m * 4 + e] = base + pre; }
    else t2s[m * 4 + e] = -1;
    base += __popcll(mask);
  }
  if (lane == 0) cnt[e] = base;
  for (int s = base + lane; s < 2048; s += 64) s2t[e * 2048 + s] = 0;  // pad
}

// out = x2 + sum_e wf[m,e] * (t3[slot(m,e)] + elb[e])   (expert order)
__global__ void final2_k(const float* x2, const float* wf, const int* t2s,
                         const float* t3, const float* elb, float* out) {
  int m = blockIdx.x, c4 = threadIdx.x * 4;
  long long i = (long long)m * 1024 + c4;
  float4 val = *(const float4*)(x2 + i);
#pragma unroll
  for (int e = 0; e < 4; ++e) {
    int s = t2s[m * 4 + e];
    if (s < 0) continue;
    float w = wf[m * 4 + e];
    float4 v = *(const float4*)(t3 + ((long long)e * 2048 + s) * 1024 + c4);
    float4 b = *(const float4*)(elb + e * 1024 + c4);
    val.x += w * (v.x + b.x); val.y += w * (v.y + b.y);
    val.z += w * (v.z + b.z); val.w += w * (v.w + b.w);
  }
  *(float4*)(out + i) = val;
}

// ------------------------------------------------------------------ host --
extern "C" void kernel_launch(void* const* d_in, const int* in_sizes, int n_in,
                              void* d_out, int out_size, void* d_ws, size_t ws_size,
                              hipStream_t stream) {
  const float* x    = (const float*)d_in[0];
  const float* goal = (const float*)d_in[1];
  const float* mem  = (const float*)d_in[2];
  const float* n1w  = (const float*)d_in[3];
  const float* n2w  = (const float*)d_in[4];
  const float* rw   = (const float*)d_in[5];
  const float* xpw  = (const float*)d_in[6];
  const float* Amat = (const float*)d_in[7];
  const float* Dp   = (const float*)d_in[8];
  const float* gw   = (const float*)d_in[9];
  const float* gb   = (const float*)d_in[10];
  const float* sow  = (const float*)d_in[11];
  const float* qw   = (const float*)d_in[12];
  const float* kw   = (const float*)d_in[13];
  const float* vw   = (const float*)d_in[14];
  const float* ow   = (const float*)d_in[15];
  const float* qnw  = (const float*)d_in[16];
  const float* knw  = (const float*)d_in[17];
  const float* dww  = (const float*)d_in[18];
  const float* dwb  = (const float*)d_in[19];
  const float* pww  = (const float*)d_in[20];
  const float* pwb  = (const float*)d_in[21];
  const float* mgw  = (const float*)d_in[22];
  const float* ew1  = (const float*)d_in[23];
  const float* ew2  = (const float*)d_in[24];
  const float* elw  = (const float*)d_in[25];
  const float* elb  = (const float*)d_in[26];
  float* out = (float*)d_out;

  char* base = (char*)d_ws; size_t off = 0;
  auto alloc = [&](size_t b) { void* p = base + off; off += (b + 255) & ~(size_t)255; return p; };
  float* xn    = (float*)alloc(2048ull * 1024 * 4);
  u16*   xnb   = (u16*)  alloc(2048ull * 1024 * 2);
  float* wr    = (float*)alloc(2048ull * 4 * 4);
  float* ssm   = (float*)alloc(2048ull * 144 * 4);
  float* aprod = (float*)alloc(2048ull * 64 * 4);
  float* sloc  = (float*)alloc(2048ull * 64 * 4);
  float* cin   = (float*)alloc(2048ull * 64 * 4);
  float* ysm   = (float*)alloc(2048ull * 16 * 4);
  u16*   qpre  = (u16*)  alloc(2048ull * 1024 * 2);
  u16*   kpre  = (u16*)  alloc(2048ull * 256 * 2);
  u16*   vT    = (u16*)  alloc(2048ull * 256 * 2);
  u16*   qro   = (u16*)  alloc(2048ull * 1024 * 2);
  u16*   kro   = (u16*)  alloc(2048ull * 256 * 2);
  u16*   SA3   = (u16*)  alloc(3ull * 2048 * 1024 * 2);  // [ssdin|acat|cva]
  u16*   ssdin = SA3;
  u16*   acat  = SA3 + 2097152;
  u16*   cva   = SA3 + 4194304;
  float* t3    = (float*)base;                     // 32MB alias over R0 (slots)
  float* x2    = (float*)alloc(2048ull * 1024 * 4);
  u16*   x2b   = (u16*)  alloc(2048ull * 1024 * 2);
  float* wfull = (float*)alloc(2048ull * 4 * 4);
  int*   ecnt  = (int*)  alloc(4 * 4);
  int*   s2t   = (int*)  alloc(4ull * 2048 * 4);
  int*   t2s   = (int*)  alloc(2048ull * 4 * 4);
  float2* rtab = (float2*)alloc(32768ull * 8);
  u16* xpwt  = (u16*)alloc(256ull  * 1024 * 2);
  u16* gqkvt = (u16*)alloc(2560ull * 1024 * 2);    // [gw | qw | kw | vw]^T
  u16* w3t   = (u16*)alloc(3ull * 1024 * 1024 * 2); // [sow | ow | pww]^T
  char*  U1    = (char*) alloc(25165824ull);
  float* outs3 = (float*)U1;
  u16*   t2_4  = (u16*)  U1;                        // slot space (e_w2 out)
  char* BIG = (char*)alloc(67108864ull);
  u16* scores = (u16*)BIG;
  u16* act4   = (u16*)BIG;                          // slot space (e_w1 out)
  char* EW = (char*)alloc(33554432ull);
  u16* ew1t  = (u16*)EW;
  u16* ew2t4 = (u16*)EW;
  u16* ewlt4 = (u16*)EW;

  // ---- front weight transposes (batched) + trig table
  rtab_k<<<128, 256, 0, stream>>>(rtab);
  { WtB wb{}; wb.in[0] = gw;  wb.out[0] = gqkvt;
    wb.in[1] = qw;  wb.out[1] = gqkvt + 1048576ull;
    wb.in[2] = sow; wb.out[2] = w3t;
    wb.in[3] = ow;  wb.out[3] = w3t + 1048576ull;
    wb.in[4] = pww; wb.out[4] = w3t + 2097152ull;
    wtransb_k<<<dim3(16, 16, 5), 256, 0, stream>>>(wb, 1024, 1024, 0); }
  { WtB wb{}; wb.in[0] = kw; wb.out[0] = gqkvt + 2097152ull;
    wb.in[1] = vw; wb.out[1] = gqkvt + 2359296ull;
    wtransb_k<<<dim3(4, 16, 2), 256, 0, stream>>>(wb, 1024, 256, 0); }
  { WtB wb{}; wb.in[0] = xpw; wb.out[0] = xpwt;
    wtransb_k<<<dim3(3, 16, 1), 256, 0, stream>>>(wb, 1024, 144, 0); }

  rms1router_k<<<2048, 256, 0, stream>>>(x, goal, n1w, rw, xn, xnb, wr);

  { GemmP p{}; p.A = xnb; p.lda = 1024; p.B = xpwt; p.ldb = 1024; p.C = ssm; p.ldc = 144;
    p.M = 2048; p.N = 144; p.K = 1024;
    gemm_k<1, 64><<<dim3(3, 16, 1), 256, 0, stream>>>(p); }

  scanA_k<<<2048, 64, 0, stream>>>(ssm, Amat, aprod, sloc);
  scanB_k<<<32, 64, 0, stream>>>(aprod, sloc, cin);
  scanC_k<<<2048, 64, 0, stream>>>(ssm, Amat, cin, ysm);

  { GemmP p{}; p.A = xnb; p.lda = 1024; p.B = gqkvt; p.ldb = 1024; p.C = ssdin; p.ldc = 1024;
    p.M = 2048; p.N = 2560; p.K = 1024; p.p0 = gb; p.p1 = ysm; p.p2 = xn; p.p3 = Dp;
    p.aux0 = qpre; p.aux1 = kpre; p.aux2 = vT;
    gemm_k<10, 64><<<dim3(40, 16, 1), 256, 0, stream>>>(p); }

  rope_k<<<10240, 256, 0, stream>>>(qpre, kpre, qnw, knw, rtab, qro, kro);

  { GemmP p{}; p.A = qro; p.lda = 64; p.sAz = 65536; p.B = kro; p.ldb = 64; p.sBz = 65536;
    p.gqa = 1; p.C = scores; p.ldc = 1024; p.sCz = 1048576;
    p.M = 1024; p.N = 1024; p.K = 64; p.scale = 0.125f;
    gemm_k<5, 128><<<dim3(8, 8, 32), 256, 0, stream>>>(p); }
  { GemmP p{}; p.A = scores; p.lda = 1024; p.sAz = 1048576; p.B = vT; p.ldb = 1024; p.sBz = 65536;
    p.gqa = 1; p.C = acat; p.ldc = 1024; p.czmode = 1; p.aux0 = scores;
    p.M = 1024; p.N = 64; p.K = 1024;
    gemm_k<11, 64><<<dim3(1, 8, 32), 256, 0, stream>>>(p); }

  conv_k<<<2048, 256, 0, stream>>>(xn, dww, dwb, cva);

  { GemmP p{}; p.A = SA3; p.lda = 1024; p.sAz = 2097152; p.B = w3t; p.ldb = 1024;
    p.sBz = 1048576; p.C = outs3; p.ldc = 1024; p.sCz = 2097152;
    p.M = 2048; p.N = 1024; p.K = 1024; p.p0 = pwb;
    gemm_k<9, 64><<<dim3(16, 16, 3), 256, 0, stream>>>(p); }

  mixmoegate_k<<<2048, 256, 0, stream>>>(x, wr, outs3, mem, n2w, mgw, x2, x2b, wfull);
  escan_k<<<1, 256, 0, stream>>>(wfull, ecnt, s2t, t2s);

  // ---- MoE (top-2 routed, TN=64, ring-3 counted-vmcnt pipeline) ----
  for (int pr = 0; pr < 2; ++pr) {
    int e0 = pr * 2;
    { WtB wb{}; wb.in[0] = ew1 + (long long)e0 * 8388608; wb.out[0] = ew1t;
      wb.in[1] = ew1 + (long long)(e0 + 1) * 8388608; wb.out[1] = ew1t + 8388608ull;
      wtransb_k<<<dim3(128, 16, 2), 256, 0, stream>>>(wb, 1024, 8192, 1); }
    GemmP p{}; p.A = x2b; p.lda = 1024; p.sAz = 0; p.B = ew1t; p.ldb = 1024; p.sBz = 8192ll * 1024;
    p.C = act4 + (long long)e0 * (2048ll * 4096); p.ldc = 4096; p.sCz = 2048ll * 4096;
    p.M = 2048; p.N = 8192; p.K = 1024; p.eidx = e0; p.cnt = ecnt; p.s2t = s2t; p.xcdr = 1;
    gemm_k<8, 64, 1><<<dim3(128, 16, 2), 256, 0, stream>>>(p);
  }
  { WtB wb{};
    for (int e = 0; e < 4; ++e) {
      wb.in[e] = ew2 + (long long)e * 4194304;
      wb.out[e] = ew2t4 + (long long)e * (1024ll * 4096);
    }
    wtransb_k<<<dim3(16, 64, 4), 256, 0, stream>>>(wb, 4096, 1024, 0); }
  { GemmP p{}; p.A = act4; p.lda = 4096; p.sAz = 2048ll * 4096; p.B = ew2t4; p.ldb = 4096;
    p.sBz = 1024ll * 4096; p.C = t2_4; p.ldc = 1024; p.sCz = 2048ll * 1024;
    p.M = 2048; p.N = 1024; p.K = 4096; p.cnt = ecnt; p.xcdr = 1;
    gemm_k<0, 64, 1><<<dim3(16, 16, 4), 256, 0, stream>>>(p); }
  { WtB wb{};
    for (int e = 0; e < 4; ++e) {
      wb.in[e] = elw + (long long)e * 1048576;
      wb.out[e] = ewlt4 + (long long)e * (1024ll * 1024);
    }
    wtransb_k<<<dim3(16, 16, 4), 256, 0, stream>>>(wb, 1024, 1024, 0); }
  { GemmP p{}; p.A = t2_4; p.lda = 1024; p.sAz = 2048ll * 1024; p.B = ewlt4; p.ldb = 1024;
    p.sBz = 1024ll * 1024; p.C = t3; p.ldc = 1024; p.sCz = 2048ll * 1024;
    p.M = 2048; p.N = 1024; p.K = 1024; p.cnt = ecnt; p.xcdr = 1;
    gemm_k<1, 64, 1><<<dim3(16, 16, 4), 256, 0, stream>>>(p); }

  final2_k<<<2048, 256, 0, stream>>>(x2, wfull, t2s, t3, elb, out);
}

// Round 16
// 553.672 us; speedup vs baseline: 1.1707x; 1.1707x over previous
//
#include <hip/hip_runtime.h>
#include <hip/hip_bf16.h>
#include <cstdint>

typedef unsigned short u16;
typedef __attribute__((ext_vector_type(4))) float f32x4;
typedef __attribute__((ext_vector_type(8))) short s16x8;

#define DEV __device__ __forceinline__

DEV u16 f2bf(float x) {                       // RNE f32 -> bf16
  unsigned u = __float_as_uint(x);
  u += 0x7FFFu + ((u >> 16) & 1u);
  return (u16)(u >> 16);
}
DEV float bf2f(u16 b) { return __uint_as_float(((unsigned)b) << 16); }

DEV void gload16(const void* g, void* l) {    // async global->LDS, 16B/lane
  __builtin_amdgcn_global_load_lds(
      (const __attribute__((address_space(1))) void*)g,
      (__attribute__((address_space(3))) void*)l, 16, 0, 0);
}

template<bool MAXOP>
DEV float blockRed256(float v) {
  for (int o = 32; o; o >>= 1) {
    float t = __shfl_xor(v, o);
    v = MAXOP ? fmaxf(v, t) : v + t;
  }
  __shared__ float s[4];
  __syncthreads();
  if ((threadIdx.x & 63) == 0) s[threadIdx.x >> 6] = v;
  __syncthreads();
  return MAXOP ? fmaxf(fmaxf(s[0], s[1]), fmaxf(s[2], s[3]))
               : (s[0] + s[1] + s[2] + s[3]);
}

// ------------------------------------------------- weight transpose ------
// batched: z selects (in,out) pair. f32 (K,N) -> bf16 (N,K). ilv: swiglu.
struct WtB { const float* in[8]; u16* out[8]; };
__global__ __launch_bounds__(256) void wtransb_k(WtB wb, int K, int N, int ilv) {
  const float* __restrict__ in = wb.in[blockIdx.z];
  u16* __restrict__ out = wb.out[blockIdx.z];
  __shared__ float t[64][68];
  const int n0 = blockIdx.x * 64, k0 = blockIdx.y * 64;
  const int tt = threadIdx.x;
  const int kl = tt >> 4, nl = (tt & 15) * 4;
#pragma unroll
  for (int i = 0; i < 4; ++i) {
    int k = kl + i * 16;
    float4 v{0.f, 0.f, 0.f, 0.f};
    if (n0 + nl + 3 < N) {
      v = *(const float4*)(in + (long long)(k0 + k) * N + n0 + nl);
    } else {
      for (int j = 0; j < 4; ++j)
        if (n0 + nl + j < N) ((float*)&v)[j] = in[(long long)(k0 + k) * N + n0 + nl + j];
    }
    t[nl + 0][k] = v.x; t[nl + 1][k] = v.y; t[nl + 2][k] = v.z; t[nl + 3][k] = v.w;
  }
  __syncthreads();
  const int n = tt >> 2, kq = (tt & 3) * 16;
  if (n0 + n < N) {
    s16x8 o0, o1;
#pragma unroll
    for (int j = 0; j < 8; ++j) { o0[j] = (short)f2bf(t[n][kq + j]); o1[j] = (short)f2bf(t[n][kq + 8 + j]); }
    int c = n0 + n;
    int r = ilv ? ((((c & 4095) >> 4) << 5) + ((c >> 12) << 4) + (c & 15)) : c;
    u16* op = out + (long long)r * K + k0 + kq;
    *(s16x8*)op = o0; *(s16x8*)(op + 8) = o1;
  }
}

// ---------------------------------------------------------------- GEMM ----
struct GemmP {
  const u16* A; int lda; long long sAz;
  const u16* B; int ldb; long long sBz;
  void* C; int ldc; long long sCz;
  int M, N, K;
  int gqa;      // 1: B batch index = (z>>4)*4 + ((z&15)>>2)   (GQA 16q/4kv)
  int czmode;   // 1: C base = b*1048576 + h*64  (attn concat store)
  const float *p0, *p1, *p2, *p3;
  float scale; int eidx;
  u16 *aux0, *aux1, *aux2;   // qkv routing: qpre, kpre, vT ; EPI11: scores
  const int* cnt;            // per-expert routed token counts (MoE)
  const int* s2t;            // slot -> token map (MoE A-row gather)
  int xcdr;                  // 1: XCD-contiguous bx raster (by fastest)
};

// ---- 128xTN tile, 4 waves, double-buffered — ALL GEMMs -----------------
// EPI: 0 bf16, 1 f32, 5 scaled bf16, 8 fused swiglu (interleaved B rows),
//      9 batched3 f32 (+pwb if z==2), 10 gate+qkv combined,
//      11 PV with fused softmax (A rows block-private).
// Routed MoE: p.cnt -> early exit; p.s2t -> A-row gather; p.xcdr -> raster.
// NOTE (R15): ring-3 counted-vmcnt variant REGRESSED here — 3rd buffer
// (73.7KB LDS) dropped 3->2 blocks/CU; at TN=64 the 2-phase drain is
// already hidden by TLP. Keep 2-phase.
template<int EPI, int TN>
__global__ __launch_bounds__(256) void gemm_k(GemmP p) {
  constexpr int NF = TN / 32;                 // B fragments per wave
  __shared__ u16 Al[2][128 * 64];
  __shared__ u16 Bl[2][TN * 64];
  __shared__ float sminv[128];
  int bx = blockIdx.x, by = blockIdx.y, z = blockIdx.z;
  if (p.xcdr) {
    const int nx = gridDim.x, ny = gridDim.y;
    const int chunk = nx >> 3;
    int flat = (blockIdx.z * ny + blockIdx.y) * nx + blockIdx.x;
    int c = flat & 7, i = flat >> 3;
    by = i % ny;
    int rest = i / ny;
    bx = c * chunk + rest % chunk;
    z = rest / chunk;
  }
  const int t = threadIdx.x;
  const int lane = t & 63, wid = t >> 6;
  const int wm = wid >> 1, wn = wid & 1;
  const int m0 = by * 128, n0 = bx * TN;
  if (p.cnt && m0 >= p.cnt[p.eidx + z]) return;      // routed-MoE early exit
  const int* s2te = p.s2t ? p.s2t + (p.eidx + z) * 2048 : nullptr;

  const u16* Ab = p.A + (long long)z * p.sAz;
  const u16* Bb = p.B + (p.gqa ? (long long)(((z >> 4) << 2) + ((z & 15) >> 2)) * p.sBz
                               : (long long)z * p.sBz);
  const int sr = lane >> 3;                 // sub-row 0..7
  const int sg = (lane & 7) ^ sr;           // pre-swizzled k-group
  long long pao[4]; int lao[4];
  long long pbo[NF]; int lbo[NF];
#pragma unroll
  for (int c = 0; c < 4; ++c) {
    int rbase = c * 32 + wid * 8;
    int ra = m0 + rbase + sr; if (ra > p.M - 1) ra = p.M - 1;
    if (s2te) ra = s2te[ra];                // slot -> token gather
    pao[c] = (long long)ra * p.lda + sg * 8;
    lao[c] = rbase * 64;
  }
#pragma unroll
  for (int c = 0; c < NF; ++c) {
    int rbase = c * 32 + wid * 8;
    int rb = n0 + rbase + sr; if (rb > p.N - 1) rb = p.N - 1;
    pbo[c] = (long long)rb * p.ldb + sg * 8;
    lbo[c] = rbase * 64;
  }

  if (EPI == 11) {
    // fused softmax over this block's exclusive 128 score rows (K=1024).
    int r = t >> 1, h2 = t & 1;
    u16* rp = p.aux0 + (long long)z * p.sAz + (long long)(m0 + r) * 1024 + h2 * 8;
    float mx = -1e30f;
    for (int it = 0; it < 64; ++it) {
      s16x8 v = *(const s16x8*)(rp + it * 16);
#pragma unroll
      for (int q = 0; q < 8; ++q) mx = fmaxf(mx, bf2f((u16)v[q]));
    }
    mx = fmaxf(mx, __shfl_xor(mx, 1));
    float sum = 0.f;
    for (int it = 0; it < 64; ++it) {
      s16x8 v = *(s16x8*)(rp + it * 16);
      s16x8 o;
#pragma unroll
      for (int q = 0; q < 8; ++q) {
        float e = __expf(bf2f((u16)v[q]) - mx);
        sum += e;
        o[q] = (short)f2bf(e);
      }
      *(s16x8*)(rp + it * 16) = o;
    }
    sum += __shfl_xor(sum, 1);
    if (!h2) sminv[r] = 1.f / sum;
    asm volatile("s_waitcnt vmcnt(0)" ::: "memory");  // writes visible in L2
    __syncthreads();
  }

  f32x4 acc[4][NF];
#pragma unroll
  for (int i = 0; i < 4; ++i)
#pragma unroll
    for (int j = 0; j < NF; ++j) acc[i][j] = f32x4{0.f, 0.f, 0.f, 0.f};

#pragma unroll
  for (int c = 0; c < 4; ++c) gload16(Ab + pao[c], &Al[0][lao[c]]);
#pragma unroll
  for (int c = 0; c < NF; ++c) gload16(Bb + pbo[c], &Bl[0][lbo[c]]);
  __syncthreads();

  const int lr = lane & 15, lk = lane >> 4;
  int cur = 0;
  for (int k0 = 0; k0 < p.K; k0 += 64) {
    int nxt = cur ^ 1;
    if (k0 + 64 < p.K) {
#pragma unroll
      for (int c = 0; c < 4; ++c) gload16(Ab + pao[c] + k0 + 64, &Al[nxt][lao[c]]);
#pragma unroll
      for (int c = 0; c < NF; ++c) gload16(Bb + pbo[c] + k0 + 64, &Bl[nxt][lbo[c]]);
    }
#pragma unroll
    for (int kk = 0; kk < 2; ++kk) {
      s16x8 af[4], bfr[NF];
      int g = kk * 4 + lk;
#pragma unroll
      for (int i = 0; i < 4; ++i) {
        int ra = wm * 64 + i * 16 + lr;
        af[i] = *(const s16x8*)&Al[cur][ra * 64 + ((g ^ (ra & 7)) * 8)];
      }
#pragma unroll
      for (int j = 0; j < NF; ++j) {
        int rb = wn * (TN / 2) + j * 16 + lr;
        bfr[j] = *(const s16x8*)&Bl[cur][rb * 64 + ((g ^ (rb & 7)) * 8)];
      }
#pragma unroll
      for (int i = 0; i < 4; ++i)
#pragma unroll
        for (int j = 0; j < NF; ++j)
          acc[i][j] = __builtin_amdgcn_mfma_f32_16x16x32_bf16(af[i], bfr[j], acc[i][j], 0, 0, 0);
    }
    __syncthreads();
    cur = nxt;
  }

  long long cb;
  if (p.czmode == 1) { int b = z >> 4, h = z & 15; cb = (long long)b * 1048576 + h * 64; }
  else cb = (long long)z * p.sCz;
  const int lq = lane >> 4;

  if (EPI == 8) {                      // fused swiglu (interleaved B rows)
#pragma unroll
    for (int i = 0; i < 4; ++i) {
#pragma unroll
      for (int u = 0; u < NF / 2; ++u) {
        int pcol = (n0 >> 1) + wn * (TN / 4) + u * 16 + lr;
#pragma unroll
        for (int q = 0; q < 4; ++q) {
          int row = m0 + wm * 64 + i * 16 + lq * 4 + q;
          float a = acc[i][2 * u][q], gg = acc[i][2 * u + 1][q];
          ((u16*)p.C)[cb + (long long)row * p.ldc + pcol] =
              f2bf(a / (1.f + __expf(-a)) * gg);
        }
      }
    }
    return;
  }
#pragma unroll
  for (int i = 0; i < 4; ++i) {
#pragma unroll
    for (int j = 0; j < NF; ++j) {
      int col = n0 + wn * (TN / 2) + j * 16 + lr;
      if (col >= p.N) continue;
#pragma unroll
      for (int q = 0; q < 4; ++q) {
        int row = m0 + wm * 64 + i * 16 + lq * 4 + q;
        float v = acc[i][j][q];
        if (EPI == 0) {          // plain bf16 store
          ((u16*)p.C)[cb + (long long)row * p.ldc + col] = f2bf(v);
        } else if (EPI == 1) {   // plain f32 store
          ((float*)p.C)[cb + (long long)row * p.ldc + col] = v;
        } else if (EPI == 5) {   // scaled bf16 (attention scores)
          ((u16*)p.C)[cb + (long long)row * p.ldc + col] = f2bf(v * p.scale);
        } else if (EPI == 9) {   // batched3 {ssd_o, o, pw}: f32 (+bias z==2)
          float add = (z == 2) ? p.p0[col] : 0.f;
          ((float*)p.C)[cb + (long long)row * p.ldc + col] = v + add;
        } else if (EPI == 11) {  // PV: row-normalize by softmax denom
          float sc = sminv[wm * 64 + i * 16 + lq * 4 + q];
          ((u16*)p.C)[cb + (long long)row * p.ldc + col] = f2bf(v * sc);
        } else if (EPI == 10) {  // gate (col<1024) + qkv routing
          if (col < 1024) {
            float gg = 1.f / (1.f + __expf(-(v + p.p0[col])));
            float yv = p.p1[row * 16 + (col >> 6)] +
                       p.p2[(long long)row * 1024 + col] * p.p3[col >> 6];
            ((u16*)p.C)[(long long)row * p.ldc + col] = f2bf(gg * yv);
          } else {
            int c2 = col - 1024;
            if (c2 < 1024) {
              p.aux0[(long long)row * 1024 + c2] = f2bf(v);
            } else if (c2 < 1280) {
              p.aux1[(long long)row * 256 + (c2 - 1024)] = f2bf(v);
            } else {
              int cc = c2 - 1280;
              int b = row >> 10, l = row & 1023, kvh = cc >> 6, d = cc & 63;
              p.aux2[(((long long)(b * 4 + kvh) * 64 + d) << 10) + l] = f2bf(v);
            }
          }
        }
      }
    }
  }
}

// --------------------------------------------------------- small kernels --
__global__ void rms1router_k(const float* x, const float* goal, const float* w,
                             const float* rw, float* xn, u16* xnb, float* wout) {
  int m = blockIdx.x, t = threadIdx.x;
  const float* xr = x + (long long)m * 1024;
  float v[4]; float ss = 0.f;
#pragma unroll
  for (int i = 0; i < 4; ++i) { v[i] = xr[t + i * 256]; ss += v[i] * v[i]; }
  ss = blockRed256<false>(ss);
  float r = rsqrtf(ss * (1.f / 1024.f) + 1e-6f);
  float a[4] = {0.f, 0.f, 0.f, 0.f};
#pragma unroll
  for (int i = 0; i < 4; ++i) {
    int c = t + i * 256;
    float o = v[i] * r * w[c] + goal[(long long)m * 1024 + c];
    xn[(long long)m * 1024 + c] = o;
    xnb[(long long)m * 1024 + c] = f2bf(o);
    const float* rr = rw + c * 4;
    a[0] += o * rr[0]; a[1] += o * rr[1]; a[2] += o * rr[2]; a[3] += o * rr[3];
  }
#pragma unroll
  for (int j = 0; j < 4; ++j) a[j] = blockRed256<false>(a[j]);
  if (t == 0) {
    float mx = fmaxf(fmaxf(a[0], a[1]), fmaxf(a[2], a[3]));
    float e[4]; float s = 0.f;
    for (int j = 0; j < 4; ++j) { e[j] = __expf(a[j] - mx); s += e[j]; }
    const float mix[4] = {0.5f, 0.2f, 0.15f, 0.15f};
    float ws = 0.f;
    for (int j = 0; j < 4; ++j) { e[j] = e[j] / s * mix[j]; ws += e[j]; }
    for (int j = 0; j < 4; ++j) wout[m * 4 + j] = e[j] / ws;
  }
}

DEV float softplus_f(float x) { return x > 15.f ? x : log1pf(__expf(x)); }

__global__ void scanA_k(const float* ssm, const float* A, float* aprod, float* sloc) {
  int blk = blockIdx.x, n = threadIdx.x;
  int c = blk & 63, h = (blk >> 6) & 15, b = blk >> 10;
  float Ah = A[h * 64 + n];
  float ap = 1.f, s = 0.f;
  int l0 = c * 16;
  for (int j = 0; j < 16; ++j) {
    long long off = (long long)(b * 1024 + l0 + j) * 144;
    float d = softplus_f(ssm[off + 128 + h] + ssm[off + n]);
    float a = __expf(d * Ah);
    s = a * s + d * d;
    ap *= a;
  }
  long long o = (long long)blk * 64 + n;
  aprod[o] = ap; sloc[o] = s;
}

__global__ void scanB_k(const float* aprod, const float* sloc, float* cin) {
  int bh = blockIdx.x, n = threadIdx.x;
  float carry = 0.f;
  for (int c = 0; c < 64; ++c) {
    long long o = (long long)(bh * 64 + c) * 64 + n;
    cin[o] = carry;
    carry = aprod[o] * carry + sloc[o];
  }
}

__global__ void scanC_k(const float* ssm, const float* A, const float* cin, float* ysm) {
  int blk = blockIdx.x, n = threadIdx.x;
  int c = blk & 63, h = (blk >> 6) & 15, b = blk >> 10;
  float Ah = A[h * 64 + n];
  float s = cin[(long long)blk * 64 + n];
  int l0 = c * 16;
  for (int j = 0; j < 16; ++j) {
    long long off = (long long)(b * 1024 + l0 + j) * 144;
    float d = softplus_f(ssm[off + 128 + h] + ssm[off + n]);
    float a = __expf(d * Ah);
    s = a * s + d * d;
    float yv = s * ssm[off + 64 + n];
    for (int o2 = 32; o2; o2 >>= 1) yv += __shfl_xor(yv, o2);
    if (n == 0) ysm[(long long)(b * 1024 + l0 + j) * 16 + h] = yv;
  }
}

__global__ void rtab_k(float2* rt) {
  int i = blockIdx.x * 256 + threadIdx.x;    // 32768 = 1024 x 32
  int l = i >> 5, f = i & 31;
  float fr = (float)l * powf(10000.f, -(float)f * (1.f / 32.f));
  rt[i] = float2{cosf(fr), sinf(fr)};
}

__global__ void rope_k(const u16* qpre, const u16* kpre, const float* qnw,
                       const float* knw, const float2* rtab, u16* qro, u16* kro) {
  int rid = blockIdx.x * 4 + (threadIdx.x >> 6);
  int lane = threadIdx.x & 63;
  float v; const float* nw; int l; u16* dst;
  if (rid < 32768) {
    int b = rid >> 14, h = (rid >> 10) & 15; l = rid & 1023;
    v = bf2f(qpre[(long long)(b * 1024 + l) * 1024 + h * 64 + lane]);
    nw = qnw; dst = qro + (long long)rid * 64;
  } else {
    int r2 = rid - 32768;
    int b = r2 >> 12, kvh = (r2 >> 10) & 3; l = r2 & 1023;
    v = bf2f(kpre[(long long)(b * 1024 + l) * 256 + kvh * 64 + lane]);
    nw = knw; dst = kro + (long long)r2 * 64;
  }
  float ss = v * v;
  for (int o = 32; o; o >>= 1) ss += __shfl_xor(ss, o);
  float r = rsqrtf(ss * (1.f / 64.f) + 1e-6f);
  float vn = v * r * nw[lane];
  float pt = __shfl_xor(vn, 32);
  float2 cs = rtab[l * 32 + (lane & 31)];
  float o2 = vn * cs.x + ((lane < 32) ? -pt : pt) * cs.y;
  dst[lane] = f2bf(o2);
}

__global__ void conv_k(const float* xn, const float* dww, const float* dwb, u16* outb) {
  int m = blockIdx.x; int l = m & 1023;
#pragma unroll
  for (int i = 0; i < 4; ++i) {
    int d = threadIdx.x + i * 256;
    float xm = l > 0    ? xn[(long long)(m - 1) * 1024 + d] : 0.f;
    float x0 =            xn[(long long)m * 1024 + d];
    float xp = l < 1023 ? xn[(long long)(m + 1) * 1024 + d] : 0.f;
    float dv = xm * dww[d * 3] + x0 * dww[d * 3 + 1] + xp * dww[d * 3 + 2] + dwb[d];
    outb[(long long)m * 1024 + d] = f2bf(dv / (1.f + __expf(-dv)));
  }
}

__global__ void mixmoegate_k(const float* x, const float* w, const float* o3,
                             const float* mem, const float* n2w, const float* mg,
                             float* x2, u16* x2b, float* wf) {
  int m = blockIdx.x, t = threadIdx.x;
  float w0 = w[m * 4], w1 = w[m * 4 + 1], w2 = w[m * 4 + 2], w3 = w[m * 4 + 3];
  float ss = 0.f, a[4] = {0.f, 0.f, 0.f, 0.f};
#pragma unroll
  for (int j = 0; j < 4; ++j) {
    int c = t + j * 256;
    long long i = (long long)m * 1024 + c;
    float v = x[i] + w0 * o3[i] + w1 * o3[i + 2097152] + w2 * o3[i + 4194304] +
              w3 * mem[i];
    x2[i] = v; x2b[i] = f2bf(v);
    ss += v * v;
    float vw = v * n2w[c];
    const float* g = mg + c * 4;
    a[0] += vw * g[0]; a[1] += vw * g[1]; a[2] += vw * g[2]; a[3] += vw * g[3];
  }
  ss = blockRed256<false>(ss);
#pragma unroll
  for (int j = 0; j < 4; ++j) a[j] = blockRed256<false>(a[j]);
  if (t == 0) {
    float r = rsqrtf(ss * (1.f / 1024.f) + 1e-6f);
    float mx = -1e30f;
    for (int j = 0; j < 4; ++j) { a[j] *= r; mx = fmaxf(mx, a[j]); }
    float e[4]; float s = 0.f;
    for (int j = 0; j < 4; ++j) { e[j] = __expf(a[j] - mx); s += e[j]; }
    for (int j = 0; j < 4; ++j) e[j] /= s;
    int i0 = 0;
    for (int j = 1; j < 4; ++j) if (e[j] > e[i0]) i0 = j;
    int i1 = -1;
    for (int j = 0; j < 4; ++j) { if (j == i0) continue; if (i1 < 0 || e[j] > e[i1]) i1 = j; }
    for (int j = 0; j < 4; ++j) wf[m * 4 + j] = (j == i0 || j == i1) ? e[j] : 0.f;
  }
}

// deterministic expert routing: ballot prefix-scan. 1 block, 4 waves.
__global__ void escan_k(const float* wf, int* cnt, int* s2t, int* t2s) {
  int e = threadIdx.x >> 6, lane = threadIdx.x & 63;
  int base = 0;
  for (int c = 0; c < 32; ++c) {
    int m = c * 64 + lane;
    bool r = wf[m * 4 + e] != 0.f;
    unsigned long long mask = __ballot(r);
    int pre = __popcll(mask & ((1ull << lane) - 1ull));
    if (r) { s2t[e * 2048 + base + pre] = m; t2s[m * 4 + e] = base + pre; }
    else t2s[m * 4 + e] = -1;
    base += __popcll(mask);
  }
  if (lane == 0) cnt[e] = base;
  for (int s = base + lane; s < 2048; s += 64) s2t[e * 2048 + s] = 0;  // pad
}

// out = x2 + sum_e wf[m,e] * (t3[slot(m,e)] + elb[e])   (expert order)
__global__ void final2_k(const float* x2, const float* wf, const int* t2s,
                         const float* t3, const float* elb, float* out) {
  int m = blockIdx.x, c4 = threadIdx.x * 4;
  long long i = (long long)m * 1024 + c4;
  float4 val = *(const float4*)(x2 + i);
#pragma unroll
  for (int e = 0; e < 4; ++e) {
    int s = t2s[m * 4 + e];
    if (s < 0) continue;
    float w = wf[m * 4 + e];
    float4 v = *(const float4*)(t3 + ((long long)e * 2048 + s) * 1024 + c4);
    float4 b = *(const float4*)(elb + e * 1024 + c4);
    val.x += w * (v.x + b.x); val.y += w * (v.y + b.y);
    val.z += w * (v.z + b.z); val.w += w * (v.w + b.w);
  }
  *(float4*)(out + i) = val;
}

// ------------------------------------------------------------------ host --
extern "C" void kernel_launch(void* const* d_in, const int* in_sizes, int n_in,
                              void* d_out, int out_size, void* d_ws, size_t ws_size,
                              hipStream_t stream) {
  const float* x    = (const float*)d_in[0];
  const float* goal = (const float*)d_in[1];
  const float* mem  = (const float*)d_in[2];
  const float* n1w  = (const float*)d_in[3];
  const float* n2w  = (const float*)d_in[4];
  const float* rw   = (const float*)d_in[5];
  const float* xpw  = (const float*)d_in[6];
  const float* Amat = (const float*)d_in[7];
  const float* Dp   = (const float*)d_in[8];
  const float* gw   = (const float*)d_in[9];
  const float* gb   = (const float*)d_in[10];
  const float* sow  = (const float*)d_in[11];
  const float* qw   = (const float*)d_in[12];
  const float* kw   = (const float*)d_in[13];
  const float* vw   = (const float*)d_in[14];
  const float* ow   = (const float*)d_in[15];
  const float* qnw  = (const float*)d_in[16];
  const float* knw  = (const float*)d_in[17];
  const float* dww  = (const float*)d_in[18];
  const float* dwb  = (const float*)d_in[19];
  const float* pww  = (const float*)d_in[20];
  const float* pwb  = (const float*)d_in[21];
  const float* mgw  = (const float*)d_in[22];
  const float* ew1  = (const float*)d_in[23];
  const float* ew2  = (const float*)d_in[24];
  const float* elw  = (const float*)d_in[25];
  const float* elb  = (const float*)d_in[26];
  float* out = (float*)d_out;

  char* base = (char*)d_ws; size_t off = 0;
  auto alloc = [&](size_t b) { void* p = base + off; off += (b + 255) & ~(size_t)255; return p; };
  float* xn    = (float*)alloc(2048ull * 1024 * 4);
  u16*   xnb   = (u16*)  alloc(2048ull * 1024 * 2);
  float* wr    = (float*)alloc(2048ull * 4 * 4);
  float* ssm   = (float*)alloc(2048ull * 144 * 4);
  float* aprod = (float*)alloc(2048ull * 64 * 4);
  float* sloc  = (float*)alloc(2048ull * 64 * 4);
  float* cin   = (float*)alloc(2048ull * 64 * 4);
  float* ysm   = (float*)alloc(2048ull * 16 * 4);
  u16*   qpre  = (u16*)  alloc(2048ull * 1024 * 2);
  u16*   kpre  = (u16*)  alloc(2048ull * 256 * 2);
  u16*   vT    = (u16*)  alloc(2048ull * 256 * 2);
  u16*   qro   = (u16*)  alloc(2048ull * 1024 * 2);
  u16*   kro   = (u16*)  alloc(2048ull * 256 * 2);
  u16*   SA3   = (u16*)  alloc(3ull * 2048 * 1024 * 2);  // [ssdin|acat|cva]
  u16*   ssdin = SA3;
  u16*   acat  = SA3 + 2097152;
  u16*   cva   = SA3 + 4194304;
  float* t3    = (float*)base;                     // 32MB alias over R0 (slots)
  float* x2    = (float*)alloc(2048ull * 1024 * 4);
  u16*   x2b   = (u16*)  alloc(2048ull * 1024 * 2);
  float* wfull = (float*)alloc(2048ull * 4 * 4);
  int*   ecnt  = (int*)  alloc(4 * 4);
  int*   s2t   = (int*)  alloc(4ull * 2048 * 4);
  int*   t2s   = (int*)  alloc(2048ull * 4 * 4);
  float2* rtab = (float2*)alloc(32768ull * 8);
  u16* xpwt  = (u16*)alloc(256ull  * 1024 * 2);
  u16* gqkvt = (u16*)alloc(2560ull * 1024 * 2);    // [gw | qw | kw | vw]^T
  u16* w3t   = (u16*)alloc(3ull * 1024 * 1024 * 2); // [sow | ow | pww]^T
  char*  U1    = (char*) alloc(25165824ull);
  float* outs3 = (float*)U1;
  u16*   t2_4  = (u16*)  U1;                        // slot space (e_w2 out)
  char* BIG = (char*)alloc(67108864ull);
  u16* scores = (u16*)BIG;
  u16* act4   = (u16*)BIG;                          // slot space (e_w1 out)
  char* EW = (char*)alloc(33554432ull);
  u16* ew1t  = (u16*)EW;
  u16* ew2t4 = (u16*)EW;
  u16* ewlt4 = (u16*)EW;

  // ---- front weight transposes (batched) + trig table
  rtab_k<<<128, 256, 0, stream>>>(rtab);
  { WtB wb{}; wb.in[0] = gw;  wb.out[0] = gqkvt;
    wb.in[1] = qw;  wb.out[1] = gqkvt + 1048576ull;
    wb.in[2] = sow; wb.out[2] = w3t;
    wb.in[3] = ow;  wb.out[3] = w3t + 1048576ull;
    wb.in[4] = pww; wb.out[4] = w3t + 2097152ull;
    wtransb_k<<<dim3(16, 16, 5), 256, 0, stream>>>(wb, 1024, 1024, 0); }
  { WtB wb{}; wb.in[0] = kw; wb.out[0] = gqkvt + 2097152ull;
    wb.in[1] = vw; wb.out[1] = gqkvt + 2359296ull;
    wtransb_k<<<dim3(4, 16, 2), 256, 0, stream>>>(wb, 1024, 256, 0); }
  { WtB wb{}; wb.in[0] = xpw; wb.out[0] = xpwt;
    wtransb_k<<<dim3(3, 16, 1), 256, 0, stream>>>(wb, 1024, 144, 0); }

  rms1router_k<<<2048, 256, 0, stream>>>(x, goal, n1w, rw, xn, xnb, wr);

  { GemmP p{}; p.A = xnb; p.lda = 1024; p.B = xpwt; p.ldb = 1024; p.C = ssm; p.ldc = 144;
    p.M = 2048; p.N = 144; p.K = 1024;
    gemm_k<1, 64><<<dim3(3, 16, 1), 256, 0, stream>>>(p); }

  scanA_k<<<2048, 64, 0, stream>>>(ssm, Amat, aprod, sloc);
  scanB_k<<<32, 64, 0, stream>>>(aprod, sloc, cin);
  scanC_k<<<2048, 64, 0, stream>>>(ssm, Amat, cin, ysm);

  { GemmP p{}; p.A = xnb; p.lda = 1024; p.B = gqkvt; p.ldb = 1024; p.C = ssdin; p.ldc = 1024;
    p.M = 2048; p.N = 2560; p.K = 1024; p.p0 = gb; p.p1 = ysm; p.p2 = xn; p.p3 = Dp;
    p.aux0 = qpre; p.aux1 = kpre; p.aux2 = vT;
    gemm_k<10, 64><<<dim3(40, 16, 1), 256, 0, stream>>>(p); }

  rope_k<<<10240, 256, 0, stream>>>(qpre, kpre, qnw, knw, rtab, qro, kro);

  { GemmP p{}; p.A = qro; p.lda = 64; p.sAz = 65536; p.B = kro; p.ldb = 64; p.sBz = 65536;
    p.gqa = 1; p.C = scores; p.ldc = 1024; p.sCz = 1048576;
    p.M = 1024; p.N = 1024; p.K = 64; p.scale = 0.125f;
    gemm_k<5, 128><<<dim3(8, 8, 32), 256, 0, stream>>>(p); }
  { GemmP p{}; p.A = scores; p.lda = 1024; p.sAz = 1048576; p.B = vT; p.ldb = 1024; p.sBz = 65536;
    p.gqa = 1; p.C = acat; p.ldc = 1024; p.czmode = 1; p.aux0 = scores;
    p.M = 1024; p.N = 64; p.K = 1024;
    gemm_k<11, 64><<<dim3(1, 8, 32), 256, 0, stream>>>(p); }

  conv_k<<<2048, 256, 0, stream>>>(xn, dww, dwb, cva);

  { GemmP p{}; p.A = SA3; p.lda = 1024; p.sAz = 2097152; p.B = w3t; p.ldb = 1024;
    p.sBz = 1048576; p.C = outs3; p.ldc = 1024; p.sCz = 2097152;
    p.M = 2048; p.N = 1024; p.K = 1024; p.p0 = pwb;
    gemm_k<9, 64><<<dim3(16, 16, 3), 256, 0, stream>>>(p); }

  mixmoegate_k<<<2048, 256, 0, stream>>>(x, wr, outs3, mem, n2w, mgw, x2, x2b, wfull);
  escan_k<<<1, 256, 0, stream>>>(wfull, ecnt, s2t, t2s);

  // ---- MoE (top-2 routed, TN=64 tiles for 3 blocks/CU, XCD raster) ----
  for (int pr = 0; pr < 2; ++pr) {
    int e0 = pr * 2;
    { WtB wb{}; wb.in[0] = ew1 + (long long)e0 * 8388608; wb.out[0] = ew1t;
      wb.in[1] = ew1 + (long long)(e0 + 1) * 8388608; wb.out[1] = ew1t + 8388608ull;
      wtransb_k<<<dim3(128, 16, 2), 256, 0, stream>>>(wb, 1024, 8192, 1); }
    GemmP p{}; p.A = x2b; p.lda = 1024; p.sAz = 0; p.B = ew1t; p.ldb = 1024; p.sBz = 8192ll * 1024;
    p.C = act4 + (long long)e0 * (2048ll * 4096); p.ldc = 4096; p.sCz = 2048ll * 4096;
    p.M = 2048; p.N = 8192; p.K = 1024; p.eidx = e0; p.cnt = ecnt; p.s2t = s2t; p.xcdr = 1;
    gemm_k<8, 64><<<dim3(128, 16, 2), 256, 0, stream>>>(p);
  }
  { WtB wb{};
    for (int e = 0; e < 4; ++e) {
      wb.in[e] = ew2 + (long long)e * 4194304;
      wb.out[e] = ew2t4 + (long long)e * (1024ll * 4096);
    }
    wtransb_k<<<dim3(16, 64, 4), 256, 0, stream>>>(wb, 4096, 1024, 0); }
  { GemmP p{}; p.A = act4; p.lda = 4096; p.sAz = 2048ll * 4096; p.B = ew2t4; p.ldb = 4096;
    p.sBz = 1024ll * 4096; p.C = t2_4; p.ldc = 1024; p.sCz = 2048ll * 1024;
    p.M = 2048; p.N = 1024; p.K = 4096; p.cnt = ecnt; p.xcdr = 1;
    gemm_k<0, 64><<<dim3(16, 16, 4), 256, 0, stream>>>(p); }
  { WtB wb{};
    for (int e = 0; e < 4; ++e) {
      wb.in[e] = elw + (long long)e * 1048576;
      wb.out[e] = ewlt4 + (long long)e * (1024ll * 1024);
    }
    wtransb_k<<<dim3(16, 16, 4), 256, 0, stream>>>(wb, 1024, 1024, 0); }
  { GemmP p{}; p.A = t2_4; p.lda = 1024; p.sAz = 2048ll * 1024; p.B = ewlt4; p.ldb = 1024;
    p.sBz = 1024ll * 1024; p.C = t3; p.ldc = 1024; p.sCz = 2048ll * 1024;
    p.M = 2048; p.N = 1024; p.K = 1024; p.cnt = ecnt; p.xcdr = 1;
    gemm_k<1, 64><<<dim3(16, 16, 4), 256, 0, stream>>>(p); }

  final2_k<<<2048, 256, 0, stream>>>(x2, wfull, t2s, t3, elb, out);
}